// Round 1
// baseline (1902.802 us; speedup 1.0000x reference)
//
#include <hip/hip_runtime.h>
#include <hip/hip_bf16.h>

// Problem constants
#define S_  32
#define W_  64
#define D_  256
#define H_  256
#define G4  1024          // 4*H
#define T_  2048          // S_*W_

// Workspace byte offsets
#define X1_OFF    0u              // 2048*1024*4 = 8388608
#define HW_OFF    8388608u        // 2048*256*4  = 2097152
#define WIHT_OFF  10485760u       // 1 MB  (W_ih2 transposed [256][1024])
#define WHHT_OFF  11534336u       // 1 MB  (W_hh2 transposed)
#define HX_OFF    12582912u       // 2*32*256*2 = 32768 (bf16 h exchange, double buffered)
#define SC1_OFF   12615680u       // 2048*4
#define SV_OFF    12623872u       // 32*256*4
#define RH_OFF    12656640u       // 32*256*4
#define HX2_OFF   12689408u       // 2*256*4
#define SC2_OFF   12691456u       // 32*4
#define BAR_OFF   12691584u       // 64 ints
#define WS_NEED   12691840u

typedef short v4s __attribute__((ext_vector_type(4)));
typedef short v8s __attribute__((ext_vector_type(8)));
typedef float v4f __attribute__((ext_vector_type(4)));

__device__ __forceinline__ unsigned short f2bf(float x) {
  unsigned u = __float_as_uint(x);
  u += 0x7fffu + ((u >> 16) & 1u);      // round-to-nearest-even
  return (unsigned short)(u >> 16);
}

__device__ __forceinline__ v4f mfma16(v4s a, v4s b, v4f c) {
#if __has_builtin(__builtin_amdgcn_mfma_f32_16x16x16bf16_1k)
  return __builtin_amdgcn_mfma_f32_16x16x16bf16_1k(a, b, c, 0, 0, 0);
#else
  // zero-padded 16x16x32 fallback: A and B share the same lane->k mapping, so
  // placing values in elements 0..3 (k<16 half) of both operands pairs up correctly.
  v8s a8 = {a[0], a[1], a[2], a[3], 0, 0, 0, 0};
  v8s b8 = {b[0], b[1], b[2], b[3], 0, 0, 0, 0};
  return __builtin_amdgcn_mfma_f32_16x16x32_bf16(a8, b8, c, 0, 0, 0);
#endif
}

__device__ __forceinline__ float sigf(float x) { return 1.f / (1.f + expf(-x)); }

// Device-scope phase barrier for a few persistent workgroups.
__device__ __forceinline__ void gbar(int* bar, int target) {
  __syncthreads();
  if (threadIdx.x == 0) {
    __threadfence();
    __hip_atomic_fetch_add(bar, 1, __ATOMIC_ACQ_REL, __HIP_MEMORY_SCOPE_AGENT);
    while (__hip_atomic_load(bar, __ATOMIC_ACQUIRE, __HIP_MEMORY_SCOPE_AGENT) < target) {
      __builtin_amdgcn_s_sleep(2);
    }
    __threadfence();
  }
  __syncthreads();
}

__device__ __forceinline__ float block_reduce_sum(float v, float* red) {
  const int tid = threadIdx.x;
  red[tid] = v;
  __syncthreads();
  for (int off = 128; off > 0; off >>= 1) {
    if (tid < off) red[tid] += red[tid + off];
    __syncthreads();
  }
  float r = red[0];
  __syncthreads();
  return r;
}

// ---------------- X1 = inputs @ W_ih1^T + b1  (fp32 tiled GEMM) ----------------
__global__ __launch_bounds__(256) void x1_gemm(const float* __restrict__ inp,
                                               const float* __restrict__ Wih,
                                               const float* __restrict__ b1,
                                               float* __restrict__ X1) {
  __shared__ __align__(16) float As[32][68];   // [k][n-row]
  __shared__ __align__(16) float Bs[32][68];   // [k][m-row]
  const int bx = blockIdx.x, by = blockIdx.y;
  const int tid = threadIdx.x;
  const int tx = tid & 15, ty = tid >> 4;
  const int n0 = by * 64, m0 = bx * 64;
  const int lr = tid >> 5, lc = tid & 31;
  float acc[4][4] = {};
  for (int k0 = 0; k0 < 256; k0 += 32) {
#pragma unroll
    for (int p = 0; p < 8; ++p) {
      int r = p * 8 + lr;
      As[lc][r] = inp[(size_t)(n0 + r) * 256 + k0 + lc];
      Bs[lc][r] = Wih[(size_t)(m0 + r) * 256 + k0 + lc];
    }
    __syncthreads();
#pragma unroll
    for (int kk = 0; kk < 32; ++kk) {
      float4 av = *(const float4*)&As[kk][ty * 4];
      float4 bv = *(const float4*)&Bs[kk][tx * 4];
      const float a_[4] = {av.x, av.y, av.z, av.w};
      const float b_[4] = {bv.x, bv.y, bv.z, bv.w};
#pragma unroll
      for (int i = 0; i < 4; ++i)
#pragma unroll
        for (int j = 0; j < 4; ++j) acc[i][j] += a_[i] * b_[j];
    }
    __syncthreads();
  }
  float4 bb = *(const float4*)&b1[m0 + tx * 4];
  const float bv_[4] = {bb.x, bb.y, bb.z, bb.w};
#pragma unroll
  for (int i = 0; i < 4; ++i) {
    float4 o;
    o.x = acc[i][0] + bv_[0];
    o.y = acc[i][1] + bv_[1];
    o.z = acc[i][2] + bv_[2];
    o.w = acc[i][3] + bv_[3];
    *(float4*)&X1[(size_t)(n0 + ty * 4 + i) * 1024 + m0 + tx * 4] = o;
  }
}

// ---------------- transpose [1024][256] -> [256][1024] ----------------
__global__ __launch_bounds__(256) void transpose_k(const float* __restrict__ src,
                                                   float* __restrict__ dst) {
  __shared__ float t[32][33];
  const int bx = blockIdx.x;  // col tile (8)
  const int by = blockIdx.y;  // row tile (32)
  const int tx = threadIdx.x & 31, ty = threadIdx.x >> 5;
#pragma unroll
  for (int p = 0; p < 4; ++p) {
    int r = ty + p * 8;
    t[r][tx] = src[(size_t)(by * 32 + r) * 256 + bx * 32 + tx];
  }
  __syncthreads();
#pragma unroll
  for (int p = 0; p < 4; ++p) {
    int r = ty + p * 8;
    dst[(size_t)(bx * 32 + r) * 1024 + by * 32 + tx] = t[tx][r];
  }
}

// ---------------- word-level LSTM: fixed-point, 8 WGs, MFMA N=32 ----------------
__global__ __launch_bounds__(256, 1) void word_lstm_k(const float* __restrict__ X1,
                                                      const float* __restrict__ Whh,
                                                      const float* __restrict__ h0,
                                                      const float* __restrict__ c0,
                                                      float* __restrict__ Hwords,
                                                      unsigned short* __restrict__ Hx,
                                                      int* __restrict__ bar) {
  const int kb_ = blockIdx.x;  // 0..7, owns h-elements [32*kb_, 32*kb_+32)
  const int tid = threadIdx.x;
  const int g = tid >> 6;      // wave id == gate id (i,f,g,o)
  const int l = tid & 63;
  const int l15 = l & 15;
  const int lg4 = (l >> 4) * 4;

  __shared__ float Glds[4][32][33];                       // [gate][e_local][s]
  __shared__ float Cst[32][33];                           // [s][e_local]
  __shared__ float Hst[32][33];
  __shared__ __align__(8) unsigned short HxL[32][264];    // staged bf16 h [s][e]

  // Preload A fragments (bf16 W_hh1 slice) in 16x16x16 layout:
  // A[m][k]: m = lane%16 (+16*mb), k = 4*(lane/16)+j (+16*kk)
  v4s aw[2][16];
#pragma unroll
  for (int mb = 0; mb < 2; ++mb) {
    const float* wr = Whh + (size_t)(g * 256 + 32 * kb_ + mb * 16 + l15) * 256;
#pragma unroll
    for (int kk = 0; kk < 16; ++kk) {
      float4 wv = *(const float4*)(wr + kk * 16 + lg4);
      v4s t;
      t[0] = (short)f2bf(wv.x); t[1] = (short)f2bf(wv.y);
      t[2] = (short)f2bf(wv.z); t[3] = (short)f2bf(wv.w);
      aw[mb][kk] = t;
    }
  }

  const int ps = tid >> 3;        // sentence 0..31
  const int pe = (tid & 7) * 4;   // e_local base
  int phase = 0;

  for (int iter = 0; iter < 3; ++iter) {
    // ---- compute iteration inits (shift finals by one sentence) ----
    float h4[4], c4[4];
    if (iter == 0 || ps == 0) {
      float4 hv = *(const float4*)(h0 + 32 * kb_ + pe);
      float4 cv = *(const float4*)(c0 + 32 * kb_ + pe);
      h4[0] = hv.x; h4[1] = hv.y; h4[2] = hv.z; h4[3] = hv.w;
      c4[0] = cv.x; c4[1] = cv.y; c4[2] = cv.z; c4[3] = cv.w;
    } else {
#pragma unroll
      for (int j = 0; j < 4; ++j) {
        h4[j] = Hst[ps - 1][pe + j];
        c4[j] = Cst[ps - 1][pe + j];
      }
    }
    __syncthreads();   // all reads of old finals done before overwrite
#pragma unroll
    for (int j = 0; j < 4; ++j) {
      Hst[ps][pe + j] = h4[j];
      Cst[ps][pe + j] = c4[j];
    }
    {
      ushort4 hb;
      hb.x = f2bf(h4[0]); hb.y = f2bf(h4[1]); hb.z = f2bf(h4[2]); hb.w = f2bf(h4[3]);
      *(ushort4*)(Hx + (size_t)ps * 256 + 32 * kb_ + pe) = hb;   // buffer 0
    }
    gbar(bar, 8 * (++phase));

    for (int t = 0; t < 64; ++t) {
      const int rb = t & 1, wb = (t + 1) & 1;
      // ---- stage full bf16 h (all 32 sentences x 256 elems) into LDS ----
#pragma unroll
      for (int i = 0; i < 8; ++i) {
        int idx = tid + i * 256;            // 0..2047
        int row = idx >> 6, c4i = (idx & 63) * 4;
        *(ushort4*)&HxL[row][c4i] =
            *(const ushort4*)(Hx + (size_t)(rb * 32 + row) * 256 + c4i);
      }
      __syncthreads();
      // ---- B fragments: B[k][n]: n = lane%16 (+16*nb), k = 4*(lane/16)+j (+16*kk)
      v4s bfr[2][16];
#pragma unroll
      for (int nb = 0; nb < 2; ++nb)
#pragma unroll
        for (int kk = 0; kk < 16; ++kk)
          bfr[nb][kk] = *(const v4s*)&HxL[nb * 16 + l15][kk * 16 + lg4];
      // ---- MFMA: G[128][32] = Wslice @ H ----
      v4f acc[2][2];
      {
        v4f z; z[0] = 0.f; z[1] = 0.f; z[2] = 0.f; z[3] = 0.f;
        acc[0][0] = z; acc[0][1] = z; acc[1][0] = z; acc[1][1] = z;
      }
#pragma unroll
      for (int kk = 0; kk < 16; ++kk) {
        acc[0][0] = mfma16(aw[0][kk], bfr[0][kk], acc[0][0]);
        acc[0][1] = mfma16(aw[0][kk], bfr[1][kk], acc[0][1]);
        acc[1][0] = mfma16(aw[1][kk], bfr[0][kk], acc[1][0]);
        acc[1][1] = mfma16(aw[1][kk], bfr[1][kk], acc[1][1]);
      }
      // D[m][n]: m = 4*(lane/16)+j (+16*mb), n = lane%16 (+16*nb)
#pragma unroll
      for (int mb = 0; mb < 2; ++mb)
#pragma unroll
        for (int nb = 0; nb < 2; ++nb)
#pragma unroll
          for (int j = 0; j < 4; ++j)
            Glds[g][mb * 16 + lg4 + j][nb * 16 + l15] = acc[mb][nb][j];
      __syncthreads();
      // ---- pointwise LSTM cell update ----
      const float* x1r = X1 + ((size_t)(ps * 64 + t)) * 1024 + 32 * kb_ + pe;
      float4 xi = *(const float4*)(x1r);
      float4 xf = *(const float4*)(x1r + 256);
      float4 xg = *(const float4*)(x1r + 512);
      float4 xo = *(const float4*)(x1r + 768);
      const float xi_[4] = {xi.x, xi.y, xi.z, xi.w};
      const float xf_[4] = {xf.x, xf.y, xf.z, xf.w};
      const float xg_[4] = {xg.x, xg.y, xg.z, xg.w};
      const float xo_[4] = {xo.x, xo.y, xo.z, xo.w};
      float hn[4];
#pragma unroll
      for (int j = 0; j < 4; ++j) {
        float iv = sigf(Glds[0][pe + j][ps] + xi_[j]);
        float fv = sigf(Glds[1][pe + j][ps] + xf_[j]);
        float gv = tanhf(Glds[2][pe + j][ps] + xg_[j]);
        float ov = sigf(Glds[3][pe + j][ps] + xo_[j]);
        float cv = fv * Cst[ps][pe + j] + iv * gv;
        float hv = ov * tanhf(cv);
        Cst[ps][pe + j] = cv;
        Hst[ps][pe + j] = hv;
        hn[j] = hv;
      }
      *(float4*)(Hwords + ((size_t)(ps * 64 + t)) * 256 + 32 * kb_ + pe) =
          make_float4(hn[0], hn[1], hn[2], hn[3]);
      {
        ushort4 hb;
        hb.x = f2bf(hn[0]); hb.y = f2bf(hn[1]); hb.z = f2bf(hn[2]); hb.w = f2bf(hn[3]);
        *(ushort4*)(Hx + (size_t)(wb * 32 + ps) * 256 + 32 * kb_ + pe) = hb;
      }
      gbar(bar, 8 * (++phase));
    }
  }
}

// ---------------- word attention scores: sc1[s][w] = exp(u1 . A1U) ----------------
__global__ __launch_bounds__(256) void attn1_scores(const float* __restrict__ Hw,
                                                    const float* __restrict__ A1W,
                                                    const float* __restrict__ A1B,
                                                    const float* __restrict__ A1U,
                                                    float* __restrict__ sc1) {
  const int w = blockIdx.x, s = blockIdx.y, tid = threadIdx.x;
  __shared__ __align__(16) float Hl[256];
  __shared__ float red[256];
  const int sw = s * 64 + w;
  Hl[tid] = Hw[(size_t)sw * 256 + tid];
  __syncthreads();
  const float* base = A1W + (size_t)sw * 65536 + tid;
  float a0 = 0.f, a1 = 0.f, a2 = 0.f, a3 = 0.f;
  for (int h = 0; h < 256; h += 4) {
    float4 hv = *(const float4*)&Hl[h];
    a0 += hv.x * base[(size_t)(h + 0) * 256];
    a1 += hv.y * base[(size_t)(h + 1) * 256];
    a2 += hv.z * base[(size_t)(h + 2) * 256];
    a3 += hv.w * base[(size_t)(h + 3) * 256];
  }
  float u = tanhf(a0 + a1 + a2 + a3 + A1B[(size_t)sw * 256 + tid]);
  float p = u * A1U[(size_t)sw * 256 + tid];
  float tot = block_reduce_sum(p, red);
  if (tid == 0) sc1[sw] = expf(tot);
}

// ---------------- word attention combine: sentVec[s] = sum_w al1 * Hw ----------------
__global__ __launch_bounds__(256) void attn1_combine(const float* __restrict__ sc1,
                                                     const float* __restrict__ Hw,
                                                     float* __restrict__ sentVec) {
  const int s = blockIdx.x, tid = threadIdx.x;
  __shared__ float red[256];
  __shared__ float alw[64];
  float v = (tid < 64) ? sc1[s * 64 + tid] : 0.f;
  float tot = block_reduce_sum(v, red);
  if (tid < 64) alw[tid] = sc1[s * 64 + tid] / tot;
  __syncthreads();
  float acc = 0.f;
  const float* hb = Hw + (size_t)s * 64 * 256 + tid;
#pragma unroll 4
  for (int w = 0; w < 64; ++w) acc += hb[(size_t)w * 256] * alw[w];
  sentVec[s * 256 + tid] = acc;
}

// ---------------- sentence LSTM: 4 WGs, 32 sequential steps ----------------
__global__ __launch_bounds__(256, 1) void sent_lstm_k(const float* __restrict__ WihT,
                                                      const float* __restrict__ WhhT,
                                                      const float* __restrict__ b2,
                                                      const float* __restrict__ h20,
                                                      const float* __restrict__ c20,
                                                      const float* __restrict__ sentVec,
                                                      float* __restrict__ rowH,
                                                      float* __restrict__ Hx2,
                                                      int* __restrict__ bar) {
  const int k = blockIdx.x;  // 0..3, e-block of 64
  const int tid = threadIdx.x;
  const int g = tid >> 6, e = tid & 63;
  const int R = g * 256 + 64 * k + e;

  __shared__ float sV[32][256];
  __shared__ float X2l[32][256];
  __shared__ float Hl[256];
  __shared__ float Gl[256];
  __shared__ float Cl[64];

  for (int i = tid; i < 32 * 256; i += 256) sV[i >> 8][i & 255] = sentVec[i];
  if (tid < 64) Cl[tid] = c20[64 * k + tid];
  __syncthreads();

  {  // X2[s][R] = W_ih2[R] . sentVec[s] + b2[R]
    float acc[32];
    float bb = b2[R];
#pragma unroll
    for (int s = 0; s < 32; ++s) acc[s] = bb;
    for (int d = 0; d < 256; ++d) {
      float wv = WihT[(size_t)d * 1024 + R];
#pragma unroll
      for (int s = 0; s < 32; ++s) acc[s] += wv * sV[s][d];
    }
#pragma unroll
    for (int s = 0; s < 32; ++s) X2l[s][tid] = acc[s];
  }
  __syncthreads();

  int phase = 0;
  for (int t = 0; t < 32; ++t) {
    Hl[tid] = (t == 0) ? h20[tid] : Hx2[((t - 1) & 1) * 256 + tid];
    __syncthreads();
    float a = X2l[t][tid];
    for (int d = 0; d < 256; ++d) a += WhhT[(size_t)d * 1024 + R] * Hl[d];
    Gl[tid] = a;
    __syncthreads();
    if (tid < 64) {
      float iv = sigf(Gl[tid]);
      float fv = sigf(Gl[64 + tid]);
      float gv = tanhf(Gl[128 + tid]);
      float ov = sigf(Gl[192 + tid]);
      float cv = fv * Cl[tid] + iv * gv;
      float hv = ov * tanhf(cv);
      Cl[tid] = cv;
      Hx2[(t & 1) * 256 + 64 * k + tid] = hv;
      rowH[(size_t)t * 256 + 64 * k + tid] = hv;
    }
    gbar(bar, 4 * (++phase));
  }
}

// ---------------- sentence attention scores (query = stale last word hidden) ----------------
__global__ __launch_bounds__(256) void attn2_scores(const float* __restrict__ Hw,
                                                    const float* __restrict__ A2W,
                                                    const float* __restrict__ A2B,
                                                    const float* __restrict__ A2U,
                                                    float* __restrict__ sc2) {
  const int s = blockIdx.x, tid = threadIdx.x;
  __shared__ __align__(16) float Ll[256];
  __shared__ float red[256];
  Ll[tid] = Hw[(size_t)2047 * 256 + tid];  // Hwords[-1,-1]
  __syncthreads();
  const float* base = A2W + (size_t)s * 65536 + tid;
  float a0 = 0.f, a1 = 0.f, a2 = 0.f, a3 = 0.f;
  for (int h = 0; h < 256; h += 4) {
    float4 hv = *(const float4*)&Ll[h];
    a0 += hv.x * base[(size_t)(h + 0) * 256];
    a1 += hv.y * base[(size_t)(h + 1) * 256];
    a2 += hv.z * base[(size_t)(h + 2) * 256];
    a3 += hv.w * base[(size_t)(h + 3) * 256];
  }
  float u = tanhf(a0 + a1 + a2 + a3 + A2B[(size_t)s * 256 + tid]);
  float p = u * A2U[(size_t)s * 256 + tid];
  float tot = block_reduce_sum(p, red);
  if (tid == 0) sc2[s] = expf(tot);
}

// ---------------- final: softmax over sentences, combine, sigmoid ----------------
__global__ __launch_bounds__(256) void final_k(const float* __restrict__ sc2,
                                               const float* __restrict__ rowH,
                                               const float* __restrict__ Wf,
                                               const float* __restrict__ bf,
                                               float* __restrict__ out) {
  __shared__ float red[256];
  __shared__ float al[32];
  const int tid = threadIdx.x;
  float v = (tid < 32) ? sc2[tid] : 0.f;
  float tot = block_reduce_sum(v, red);
  if (tid < 32) al[tid] = sc2[tid] / tot;
  __syncthreads();
  float acc = 0.f;
#pragma unroll 4
  for (int s = 0; s < 32; ++s) acc += rowH[(size_t)s * 256 + tid] * al[s];
  float p = acc * Wf[tid];
  float z = block_reduce_sum(p, red);
  if (tid == 0) out[0] = 1.f / (1.f + expf(-(z + bf[0])));
}

extern "C" void kernel_launch(void* const* d_in, const int* in_sizes, int n_in,
                              void* d_out, int out_size, void* d_ws, size_t ws_size,
                              hipStream_t stream) {
  (void)in_sizes; (void)n_in; (void)out_size;
  if (ws_size < WS_NEED) return;

  const float* inputs = (const float*)d_in[0];
  const float* W_ih1  = (const float*)d_in[1];
  const float* W_hh1  = (const float*)d_in[2];
  const float* b1     = (const float*)d_in[3];
  const float* W_ih2  = (const float*)d_in[4];
  const float* W_hh2  = (const float*)d_in[5];
  const float* b2     = (const float*)d_in[6];
  const float* h1_0   = (const float*)d_in[7];
  const float* c1_0   = (const float*)d_in[8];
  const float* h2_0   = (const float*)d_in[9];
  const float* c2_0   = (const float*)d_in[10];
  const float* A1W    = (const float*)d_in[11];
  const float* A1B    = (const float*)d_in[12];
  const float* A1U    = (const float*)d_in[13];
  const float* A2W    = (const float*)d_in[14];
  const float* A2B    = (const float*)d_in[15];
  const float* A2U    = (const float*)d_in[16];
  const float* Wf     = (const float*)d_in[17];
  const float* bff    = (const float*)d_in[18];

  char* ws = (char*)d_ws;
  float* X1            = (float*)(ws + X1_OFF);
  float* Hw            = (float*)(ws + HW_OFF);
  float* WihT          = (float*)(ws + WIHT_OFF);
  float* WhhT          = (float*)(ws + WHHT_OFF);
  unsigned short* Hx   = (unsigned short*)(ws + HX_OFF);
  float* sc1           = (float*)(ws + SC1_OFF);
  float* sV            = (float*)(ws + SV_OFF);
  float* rH            = (float*)(ws + RH_OFF);
  float* Hx2           = (float*)(ws + HX2_OFF);
  float* sc2           = (float*)(ws + SC2_OFF);
  int*   bars          = (int*)(ws + BAR_OFF);

  hipMemsetAsync(bars, 0, 256, stream);
  x1_gemm<<<dim3(16, 32), 256, 0, stream>>>(inputs, W_ih1, b1, X1);
  transpose_k<<<dim3(8, 32), 256, 0, stream>>>(W_ih2, WihT);
  transpose_k<<<dim3(8, 32), 256, 0, stream>>>(W_hh2, WhhT);
  word_lstm_k<<<8, 256, 0, stream>>>(X1, W_hh1, h1_0, c1_0, Hw, Hx, bars);
  attn1_scores<<<dim3(64, 32), 256, 0, stream>>>(Hw, A1W, A1B, A1U, sc1);
  attn1_combine<<<32, 256, 0, stream>>>(sc1, Hw, sV);
  sent_lstm_k<<<4, 256, 0, stream>>>(WihT, WhhT, b2, h2_0, c2_0, sV, rH, Hx2, bars + 32);
  attn2_scores<<<32, 256, 0, stream>>>(Hw, A2W, A2B, A2U, sc2);
  final_k<<<1, 256, 0, stream>>>(sc2, rH, Wf, bff, (float*)d_out);
}